// Round 7
// baseline (324.554 us; speedup 1.0000x reference)
//
#include <hip/hip_runtime.h>
#include <hip/hip_bf16.h>
#include <cstdint>
#include <cstddef>

// Problem constants (B=4, S=4096, D=1024, DFF=4096, K_ACT=1024)
#define Bz 4
#define Sz 4096
#define Dz 1024
#define DFFz 4096
#define KACT 1024

typedef __bf16 bf16;
typedef __attribute__((ext_vector_type(8))) __bf16 bf16x8;
typedef __attribute__((ext_vector_type(4))) __bf16 bf16x4;
typedef __attribute__((ext_vector_type(4))) float f32x4;

__device__ __forceinline__ void async16(const void* g, void* l) {
  __builtin_amdgcn_global_load_lds(
      (const __attribute__((address_space(1))) void*)g,
      (__attribute__((address_space(3))) void*)l, 16, 0, 0);
}

// ---- fused prep: [0,4096) router+zero | [4096,5120) w1 transpose 64x64 |
//                  [5120,6144) w2 transpose 64x64 ----
// Transpose rewritten from 32x32 (64 B/wave stores, ~2-4x below BW) to 64x64
// with float4 reads + bf16x8 writes (1 KB/wave both sides, LDS 2-way free).
__global__ __launch_bounds__(256) void prep_k(const float* __restrict__ x,
                                              const float* __restrict__ rw,
                                              const float* __restrict__ rb,
                                              float* __restrict__ scores,
                                              float4* __restrict__ out4,
                                              const float* __restrict__ w1,
                                              bf16* __restrict__ w1T,
                                              const float* __restrict__ w2,
                                              bf16* __restrict__ w2T) {
  __shared__ float tt[64][65];
  const int bid = blockIdx.x;
  const int tid = threadIdx.x;
  if (bid < 4096) {
    int row = bid * 4 + (tid >> 6);
    int lane = tid & 63;
    const float4* xr = (const float4*)(x + (size_t)row * Dz);
    const float4* wr = (const float4*)rw;
    float acc = 0.f;
#pragma unroll
    for (int i = 0; i < 4; ++i) {
      float4 a = xr[lane + i * 64];
      float4 w = wr[lane + i * 64];
      acc += a.x * w.x + a.y * w.y + a.z * w.z + a.w * w.w;
    }
#pragma unroll
    for (int d = 32; d; d >>= 1) acc += __shfl_down(acc, d, 64);
    if (lane == 0) scores[row] = acc + rb[0];
    float4* o = out4 + (size_t)bid * 4 * (Dz / 4);
    const float4 z = make_float4(0.f, 0.f, 0.f, 0.f);
#pragma unroll
    for (int i = 0; i < 4; ++i) o[tid + i * 256] = z;
  } else {
    const float* in; bf16* outp; int R, C, bx, by;
    if (bid < 5120) {
      in = w1; outp = w1T; R = Dz; C = DFFz;           // w1[k][n] -> w1T[n][k]
      bx = (bid - 4096) & 63; by = (bid - 4096) >> 6;  // 64 n-tiles x 16 k-tiles
    } else {
      in = w2; outp = w2T; R = DFFz; C = Dz;           // w2[k][n] -> w2T[n][k]
      bx = (bid - 5120) & 15; by = (bid - 5120) >> 4;  // 16 n-tiles x 64 k-tiles
    }
    const int r0 = by * 64, c0 = bx * 64;
    // read 64x64 fp32 tile, coalesced float4 (4 threads/row, 1 KB/wave)
#pragma unroll
    for (int i = 0; i < 4; ++i) {
      int row = (tid >> 4) + i * 16;
      int col = (tid & 15) * 4;
      float4 v = *(const float4*)&in[(size_t)(r0 + row) * C + c0 + col];
      tt[row][col] = v.x; tt[row][col + 1] = v.y;
      tt[row][col + 2] = v.z; tt[row][col + 3] = v.w;
    }
    __syncthreads();
    // write transposed as bf16x8 (8 threads/row of 128 B, 1 KB/wave)
#pragma unroll
    for (int i = 0; i < 2; ++i) {
      int nl = (tid >> 3) + i * 32;
      int kl = (tid & 7) * 8;
      bf16x8 o;
#pragma unroll
      for (int j = 0; j < 8; ++j) o[j] = (bf16)tt[kl + j][nl];
      *(bf16x8*)&outp[(size_t)(c0 + nl) * R + r0 + kl] = o;
    }
  }
}

// ---- select top-K per batch, 16 tokens/block: scores staged in LDS once ----
__global__ __launch_bounds__(256) void select_gather_k(
    const float* __restrict__ x, const float* __restrict__ scores,
    int* __restrict__ sel_idx, float* __restrict__ gates, bf16* __restrict__ Xsel) {
  int b = blockIdx.x >> 8;            // 256 blocks per batch row
  int s0 = (blockIdx.x & 255) * 16;   // first of 16 tokens
  __shared__ float sc[Sz];
  __shared__ int red[16][4];
  __shared__ int rk[16];
  const int tid = threadIdx.x;
  const int wave = tid >> 6, lane = tid & 63;
  const float* srow = scores + (size_t)b * Sz;
#pragma unroll
  for (int i = 0; i < 4; ++i)
    ((float4*)sc)[tid + i * 256] = ((const float4*)srow)[tid + i * 256];
  __syncthreads();
  float mine[16];
#pragma unroll
  for (int j = 0; j < 16; ++j) mine[j] = sc[s0 + j];
  int cnt[16] = {};
  for (int t = tid; t < Sz; t += 256) {
    float o = sc[t];
#pragma unroll
    for (int j = 0; j < 16; ++j)
      cnt[j] += (o > mine[j]) || (o == mine[j] && t < s0 + j);
  }
#pragma unroll
  for (int j = 0; j < 16; ++j) {
    int c = cnt[j];
#pragma unroll
    for (int d = 32; d; d >>= 1) c += __shfl_down(c, d, 64);
    if (lane == 0) red[j][wave] = c;
  }
  __syncthreads();
  if (tid < 16) {
    int rank = red[tid][0] + red[tid][1] + red[tid][2] + red[tid][3];
    rk[tid] = rank;
    if (rank < KACT) {
      int m = b * KACT + rank;
      sel_idx[m] = s0 + tid;
      gates[m] = 1.f / (1.f + expf(-sc[s0 + tid]));
    }
  }
  __syncthreads();
#pragma unroll
  for (int j = 0; j < 16; ++j) {
    int rank = rk[j];
    if (rank >= KACT) continue;
    int m = b * KACT + rank;
    float4 v = ((const float4*)(x + ((size_t)b * Sz + s0 + j) * Dz))[tid];
    bf16x4 o = {(bf16)v.x, (bf16)v.y, (bf16)v.z, (bf16)v.w};
    ((bf16x4*)(Xsel + (size_t)m * Dz))[tid] = o;
  }
}

// ======== 256x256-tile BK=64 2-phase GEMM (supply-bound fix) ========
// R4/R5/R6 evidence: time/iter scales with staged bytes at a constant
// ~13 B/cy/CU (~8.3 TB/s aggregate) regardless of pipeline depth, barrier
// count, or BK -> the GEMMs are DATA-SUPPLY-bound. 128^2 tiles stage 512 MB
// per GEMM (= ~62 us at 8.3 TB/s = measured). 256^2 tiles halve staged bytes
// to 256 MB -> ~32 us ceiling, plus 4x MFMA-per-barrier (64/wave/body).
// Skeleton unchanged from R6 (proven correct): distinct LDS arrays (R4 alias
// fix), stage-at-top, one vmcnt(0)+lgkmcnt(0)+s_barrier per body, swizzle
//   phys = off ^ (((off>>7)&7)<<4)   (128 B rows; measured 0 conflicts)
// applied linear-dest + pre-swizzled global source + swizzled ds_read.
// 512 thr / 8 waves (2M x 4N), per-wave 128x64 out; LDS 4x32 KB = 128 KB
// (R3 proved >64 KB static OK); __launch_bounds__(512,2) caps VGPR at 256.

#define BAR_VM0 asm volatile("s_waitcnt vmcnt(0) lgkmcnt(0)\n\ts_barrier" ::: "memory")

// stage tile T (k-offset T*64 elems = T*128 B); 8 async16/thread, 64 KB total
#define STG(AS, BS, T)                                                        \
  {                                                                           \
    size_t ko_ = (size_t)(T) * 128;                                           \
    async16(pa0 + ko_, (char*)AS + Ld0);                                      \
    async16(pa1 + ko_, (char*)AS + Ld1);                                      \
    async16(pa2 + ko_, (char*)AS + Ld2);                                      \
    async16(pa3 + ko_, (char*)AS + Ld3);                                      \
    async16(pb0 + ko_, (char*)BS + Ld0);                                      \
    async16(pb1 + ko_, (char*)BS + Ld1);                                      \
    async16(pb2 + ko_, (char*)BS + Ld2);                                      \
    async16(pb3 + ko_, (char*)BS + Ld3);                                      \
  }

// one body: stage tile T+1 into AST/BST, then per k-chunk {read frags, 32
// MFMA} x2 (frags scoped per-kc to cap VGPR), then barrier if DOBAR
#define GB(ARD, BRD, AST, BST, T, DOSTAGE, DOBAR)                             \
  {                                                                           \
    if (DOSTAGE) { STG(AST, BST, (T) + 1) }                                   \
    const char* a_ = (const char*)ARD;                                        \
    const char* b_ = (const char*)BRD;                                        \
    _Pragma("unroll") for (int kc = 0; kc < 2; ++kc) {                        \
      bf16x8 af[8], bfr[4];                                                   \
      _Pragma("unroll") for (int i = 0; i < 8; ++i)                           \
        af[i] = *(const bf16x8*)(a_ + aoff[kc][i]);                           \
      _Pragma("unroll") for (int i = 0; i < 4; ++i)                           \
        bfr[i] = *(const bf16x8*)(b_ + boff[kc][i]);                          \
      __builtin_amdgcn_s_setprio(1);                                          \
      _Pragma("unroll") for (int mi = 0; mi < 8; ++mi)                        \
        _Pragma("unroll") for (int ni = 0; ni < 4; ++ni)                      \
          acc[mi][ni] = __builtin_amdgcn_mfma_f32_16x16x32_bf16(              \
              af[mi], bfr[ni], acc[mi][ni], 0, 0, 0);                         \
      __builtin_amdgcn_s_setprio(0);                                          \
    }                                                                         \
    if (DOBAR) { BAR_VM0; }                                                   \
  }

// setup: 256x256 tile, BK=64, 8 waves (2M x 4N), 128 B LDS rows.
// staging: thread covers LDS bytes Ld_j = tid*16 + j*8192 of each 32 KB stage.
#define GSETUP(APTR, BPTR, KV, KOFFB)                                         \
  const int tid = threadIdx.x;                                                \
  const int wave = tid >> 6, lane = tid & 63;                                 \
  const int quad = lane >> 4, l16 = lane & 15;                                \
  const int wm = (wave >> 2) * 128, wn = (wave & 3) * 64;                     \
  const int Ld0 = tid * 16, Ld1 = Ld0 + 8192, Ld2 = Ld0 + 16384,              \
            Ld3 = Ld0 + 24576;                                                \
  const int q0 = Ld0 ^ (((Ld0 >> 7) & 7) << 4);                               \
  const int q1 = Ld1 ^ (((Ld1 >> 7) & 7) << 4);                               \
  const int q2 = Ld2 ^ (((Ld2 >> 7) & 7) << 4);                               \
  const int q3 = Ld3 ^ (((Ld3 >> 7) & 7) << 4);                               \
  const char* pa0 = (const char*)(APTR) +                                     \
      ((size_t)(m0 + (q0 >> 7)) * (KV)) * 2 + (KOFFB) + (q0 & 127);           \
  const char* pa1 = (const char*)(APTR) +                                     \
      ((size_t)(m0 + (q1 >> 7)) * (KV)) * 2 + (KOFFB) + (q1 & 127);           \
  const char* pa2 = (const char*)(APTR) +                                     \
      ((size_t)(m0 + (q2 >> 7)) * (KV)) * 2 + (KOFFB) + (q2 & 127);           \
  const char* pa3 = (const char*)(APTR) +                                     \
      ((size_t)(m0 + (q3 >> 7)) * (KV)) * 2 + (KOFFB) + (q3 & 127);           \
  const char* pb0 = (const char*)(BPTR) +                                     \
      ((size_t)(n0 + (q0 >> 7)) * (KV)) * 2 + (KOFFB) + (q0 & 127);           \
  const char* pb1 = (const char*)(BPTR) +                                     \
      ((size_t)(n0 + (q1 >> 7)) * (KV)) * 2 + (KOFFB) + (q1 & 127);           \
  const char* pb2 = (const char*)(BPTR) +                                     \
      ((size_t)(n0 + (q2 >> 7)) * (KV)) * 2 + (KOFFB) + (q2 & 127);           \
  const char* pb3 = (const char*)(BPTR) +                                     \
      ((size_t)(n0 + (q3 >> 7)) * (KV)) * 2 + (KOFFB) + (q3 & 127);           \
  int aoff[2][8], boff[2][4];                                                 \
  _Pragma("unroll") for (int kc = 0; kc < 2; ++kc) {                          \
    _Pragma("unroll") for (int i = 0; i < 8; ++i) {                           \
      int ra = wm + i * 16 + l16;                                             \
      aoff[kc][i] = (ra * 128 + kc * 64 + quad * 16) ^ ((ra & 7) << 4);       \
    }                                                                         \
    _Pragma("unroll") for (int i = 0; i < 4; ++i) {                           \
      int rb = wn + i * 16 + l16;                                             \
      boff[kc][i] = (rb * 128 + kc * 64 + quad * 16) ^ ((rb & 7) << 4);       \
    }                                                                         \
  }                                                                           \
  f32x4 acc[8][4] = {};

// ---------------- GEMM1: H = gelu(Xsel @ w1 + b1), M=4096 N=4096 K=1024 ----
// BK=64 -> NITER=16; grid 16x16 = 256 blocks = 1/CU; staged 256 MB (was 512).
__global__ __launch_bounds__(512, 2) void gemm1_k(const bf16* __restrict__ A,
                                                  const bf16* __restrict__ Bt,
                                                  const float* __restrict__ bias,
                                                  bf16* __restrict__ H) {
  __shared__ __align__(16) bf16 A0[16384], A1[16384];  // 32 KB each
  __shared__ __align__(16) bf16 B0[16384], B1[16384];
  const int orig = blockIdx.y * 16 + blockIdx.x;               // nwg=256
  const int wgid = (orig & 7) * 32 + (orig >> 3);              // bijective XCD chunk
  const int m0 = (wgid >> 4) * 256, n0 = (wgid & 15) * 256;
  GSETUP(A, Bt, Dz, 0)
  STG(A0, B0, 0)
  BAR_VM0;  // tile 0 landed everywhere
  for (int tt = 0; tt < 7; ++tt) {   // bodies 0..13
    GB(A0, B0, A1, B1, 2 * tt + 0, 1, 1)
    GB(A1, B1, A0, B0, 2 * tt + 1, 1, 1)
  }
  GB(A0, B0, A1, B1, 14, 1, 1)   // stages tile 15 -> S1
  GB(A1, B1, A0, B0, 15, 0, 0)   // final: no stage, no barrier
  // epilogue: bias + exact GELU -> bf16  (C/D: col=lane&15, row=quad*4+reg)
#pragma unroll
  for (int mi = 0; mi < 8; ++mi) {
    int mb = m0 + wm + mi * 16 + quad * 4;
#pragma unroll
    for (int ni = 0; ni < 4; ++ni) {
      int n = n0 + wn + ni * 16 + l16;
      float bn = bias[n];
#pragma unroll
      for (int r = 0; r < 4; ++r) {
        float z = acc[mi][ni][r] + bn;
        float g = 0.5f * z * (1.f + erff(z * 0.70710678118654752f));
        H[(size_t)(mb + r) * DFFz + n] = (bf16)g;
      }
    }
  }
}

// ---- GEMM2: out[b,sel[m],:] += (H @ w2 [+ b2]) * gate, split-K=4, atomic ----
// M=4096 N=1024 Kchunk=1024 -> NITER=16; grid (4,16,4) = 256 blocks = 1/CU;
// staged 256 MB (was 512). n-tile rotated by z to decorrelate atomic targets.
// out pre-zeroed by prep_k; f32 atomicAdd is order-independent.
__global__ __launch_bounds__(512, 2) void gemm2_k(const bf16* __restrict__ A,
                                                  const bf16* __restrict__ Bt,
                                                  const float* __restrict__ b2,
                                                  const int* __restrict__ sel_idx,
                                                  const float* __restrict__ gates,
                                                  float* __restrict__ out) {
  __shared__ __align__(16) bf16 A0[16384], A1[16384];
  __shared__ __align__(16) bf16 B0[16384], B1[16384];
  const int orig = blockIdx.y * 4 + blockIdx.x;                // 64 per z-plane
  const int wgid = (orig & 7) * 8 + (orig >> 3);               // bijective XCD chunk
  const int m0 = (wgid >> 2) * 256;
  const int n0 = (((wgid & 3) + blockIdx.z) & 3) * 256;        // z-rotated n-tile
  GSETUP(A, Bt, DFFz, (size_t)blockIdx.z * 1024 * 2)
  STG(A0, B0, 0)
  BAR_VM0;
  for (int tt = 0; tt < 7; ++tt) {   // bodies 0..13
    GB(A0, B0, A1, B1, 2 * tt + 0, 1, 1)
    GB(A1, B1, A0, B0, 2 * tt + 1, 1, 1)
  }
  GB(A0, B0, A1, B1, 14, 1, 1)   // stages tile 15 -> S1
  GB(A1, B1, A0, B0, 15, 0, 0)   // final: no stage, no barrier
  // fused epilogue: (+b2 on z==0), gate, atomic scatter into zeroed out
  const bool addb = (blockIdx.z == 0);
#pragma unroll
  for (int mi = 0; mi < 8; ++mi) {
#pragma unroll
    for (int r = 0; r < 4; ++r) {
      int m = m0 + wm + mi * 16 + quad * 4 + r;
      int b = m >> 10;
      int s = sel_idx[m];
      float g = gates[m];
      float* orow = out + ((size_t)b * Sz + s) * Dz;
#pragma unroll
      for (int ni = 0; ni < 4; ++ni) {
        int n = n0 + wn + ni * 16 + l16;
        float v = acc[mi][ni][r] + (addb ? b2[n] : 0.f);
        atomicAdd(&orow[n], v * g);
      }
    }
  }
}

extern "C" void kernel_launch(void* const* d_in, const int* in_sizes, int n_in,
                              void* d_out, int out_size, void* d_ws, size_t ws_size,
                              hipStream_t stream) {
  (void)in_sizes; (void)n_in; (void)out_size; (void)ws_size;
  const float* x  = (const float*)d_in[0];
  const float* rw = (const float*)d_in[1];
  const float* rb = (const float*)d_in[2];
  const float* w1 = (const float*)d_in[3];
  const float* b1 = (const float*)d_in[4];
  const float* w2 = (const float*)d_in[5];
  const float* b2 = (const float*)d_in[6];
  float* out = (float*)d_out;

  char* ws = (char*)d_ws;
  float* scores = (float*)ws;  ws += (size_t)Bz * Sz * 4;          // 64 KB
  int*   sel_idx = (int*)ws;   ws += (size_t)Bz * KACT * 4;        // 16 KB
  float* gates = (float*)ws;   ws += (size_t)Bz * KACT * 4;        // 16 KB
  bf16*  w2T = (bf16*)ws;      ws += (size_t)Dz * DFFz * 2;        // 8 MB  [1024][4096]
  bf16*  H = (bf16*)ws;        ws += (size_t)Bz * KACT * DFFz * 2; // 32 MB [4096][4096]
  bf16*  w1T = (bf16*)ws;      ws += (size_t)DFFz * Dz * 2;        // 8 MB  [4096][1024]
  bf16*  Xsel = (bf16*)ws;     ws += (size_t)Bz * KACT * Dz * 2;   // 8 MB  [4096][1024]

  prep_k<<<6144, 256, 0, stream>>>(x, rw, rb, scores, (float4*)out, w1, w1T, w2, w2T);
  select_gather_k<<<Bz * (Sz / 16), 256, 0, stream>>>(x, scores, sel_idx, gates, Xsel);
  gemm1_k<<<dim3(16, 16), 512, 0, stream>>>(Xsel, w1T, b1, H);
  gemm2_k<<<dim3(4, 16, 4), 512, 0, stream>>>(H, w2T, b2, sel_idx, gates, out);
}